// Round 5
// baseline (319.631 us; speedup 1.0000x reference)
//
#include <hip/hip_runtime.h>

#define NTOK 4096
#define DDIM 1024
#define IDIM 704
#define NEXP 16
#define NSLOT 8192
#define MAXT 160     // m-tiles of 64 rows: worst case 128+15 < 160
#define NPAD1 768    // IDIM padded to 128 multiple for gemm1 n-dim

typedef __attribute__((ext_vector_type(8))) short bf16x8;
typedef __attribute__((ext_vector_type(4))) float f32x4;
typedef __attribute__((ext_vector_type(4))) unsigned short us4;
typedef __attribute__((ext_vector_type(8))) unsigned short us8;

__device__ __forceinline__ unsigned short f2bf(float f) {
  union { float f; unsigned int u; } v; v.f = f;
  unsigned int r = v.u + 0x7fffu + ((v.u >> 16) & 1u);
  return (unsigned short)(r >> 16);
}

__device__ __forceinline__ void gload_lds16(const void* g, void* l) {
  __builtin_amdgcn_global_load_lds((const __attribute__((address_space(1))) void*)g,
                                   (__attribute__((address_space(3))) void*)l, 16, 0, 0);
}

// ---------------- router + x->bf16 convert, fused; NO atomics ----------------
__global__ void k_router(const float* __restrict__ x, const float* __restrict__ Wg,
                         int* __restrict__ tok_e, float* __restrict__ tok_w,
                         unsigned short* __restrict__ Xb) {
  int lane = threadIdx.x & 63;
  int wv = threadIdx.x >> 6;
  int t = blockIdx.x * 4 + wv;
  const f32x4* xr = (const f32x4*)(x + (size_t)t * DDIM);
  us4* xbr = (us4*)(Xb + (size_t)t * DDIM);
  f32x4 xv[4];
#pragma unroll
  for (int c = 0; c < 4; ++c) {
    xv[c] = xr[c * 64 + lane];
    us4 o;
#pragma unroll
    for (int j = 0; j < 4; ++j) o[j] = f2bf(xv[c][j]);
    xbr[c * 64 + lane] = o;
  }
  float p[NEXP];
#pragma unroll
  for (int e = 0; e < NEXP; ++e) {
    const f32x4* wr = (const f32x4*)(Wg + (size_t)e * DDIM);
    float s = 0.f;
#pragma unroll
    for (int c = 0; c < 4; ++c) {
      f32x4 w4 = wr[c * 64 + lane];
      s += xv[c][0]*w4[0] + xv[c][1]*w4[1] + xv[c][2]*w4[2] + xv[c][3]*w4[3];
    }
    p[e] = s;
  }
#pragma unroll
  for (int off = 32; off >= 1; off >>= 1) {
#pragma unroll
    for (int e = 0; e < NEXP; ++e) p[e] += __shfl_xor(p[e], off);
  }
  int i0 = 0; float b0 = p[0];
#pragma unroll
  for (int e = 1; e < NEXP; ++e) if (p[e] > b0) { b0 = p[e]; i0 = e; }
  int i1 = -1; float b1 = -3.4e38f;
#pragma unroll
  for (int e = 0; e < NEXP; ++e) if (e != i0 && p[e] > b1) { b1 = p[e]; i1 = e; }
  if (lane == 0) {
    float w0 = 1.f / (1.f + __expf(b1 - b0));   // renormalized top-2 softmax weight
    tok_e[2*t] = i0; tok_e[2*t+1] = i1;
    tok_w[2*t] = w0; tok_w[2*t+1] = 1.f - w0;
  }
}

// ---------------- merged weight transpose+convert (W1,W3,W2 in one launch) ----------------
// [e][k][n] fp32 -> [e][npad][k] bf16, 64x64 tiles, XOR-swizzled LDS.
__global__ void k_wtrans_all(const float* __restrict__ W1, const float* __restrict__ W3,
                             const float* __restrict__ W2, unsigned short* __restrict__ W1T,
                             unsigned short* __restrict__ W3T, unsigned short* __restrict__ W2T) {
  int b = blockIdx.x;
  const float* src; unsigned short* dst;
  int ksz, nsz, npad, kx, ny, e;
  if (b < 6144) {                       // W1: 0..3071, W3: 3072..6143 (16 k-tiles x 12 n-tiles x 16 e)
    int which = (b >= 3072) ? 1 : 0;
    int tb = b - which * 3072;
    kx = tb & 15; int rest = tb >> 4; ny = rest % 12; e = rest / 12;
    ksz = DDIM; nsz = IDIM; npad = NPAD1;
    src = which ? W3 : W1; dst = which ? W3T : W1T;
  } else {                              // W2: 11 k-tiles x 16 n-tiles x 16 e
    int tb = b - 6144;
    kx = tb % 11; int rest = tb / 11; ny = rest & 15; e = rest >> 4;
    ksz = IDIM; nsz = DDIM; npad = DDIM;
    src = W2; dst = W2T;
  }
  int k0 = kx * 64, n0 = ny * 64;
  src += (size_t)e * ksz * nsz;
  dst += (size_t)e * npad * ksz;
  int t = threadIdx.x;
  if (n0 >= nsz) {                      // n-padding rows: write zeros
    int nr = t >> 3, kc0 = (t & 7) * 8;
    us8 z = (us8)(unsigned short)0;
#pragma unroll
    for (int p = 0; p < 2; ++p)
      *(us8*)(dst + (size_t)(n0 + nr + p * 32) * ksz + k0 + kc0) = z;
    return;
  }
  __shared__ unsigned short lds[64 * 64];
  int kr4 = (t >> 4) * 4, nc4 = (t & 15) * 4;
  f32x4 v[4];
#pragma unroll
  for (int j = 0; j < 4; ++j)
    v[j] = *(const f32x4*)(src + (size_t)(k0 + kr4 + j) * nsz + n0 + nc4);
  int c8 = kr4 >> 3, half = (kr4 >> 2) & 1;
#pragma unroll
  for (int i = 0; i < 4; ++i) {
    us4 o;
#pragma unroll
    for (int j = 0; j < 4; ++j) o[j] = f2bf(v[j][i]);
    int row = nc4 + i;
    int addr = row * 64 + ((c8 ^ ((row >> 2) & 7)) << 3) + half * 4;
    *(us4*)(lds + addr) = o;
  }
  __syncthreads();
  int nr = t >> 3, kc8 = t & 7;
#pragma unroll
  for (int p = 0; p < 2; ++p) {
    int row = nr + p * 32;
    us8 o = *(const us8*)(lds + row * 64 + ((kc8 ^ ((row >> 2) & 7)) << 3));
    *(us8*)(dst + (size_t)(n0 + row) * ksz + k0 + kc8 * 8) = o;
  }
}

// ---------------- count + scan: single block, no atomics; m-step 64 ----------------
__global__ void k_count_scan(const int* __restrict__ tok_e, int* __restrict__ counts,
                             int* __restrict__ offsets, int* __restrict__ ntiles,
                             int* __restrict__ tile_e, int* __restrict__ tile_m0) {
  __shared__ int h[256 * 17];
  __shared__ int counts_s[NEXP];
  int t = threadIdx.x;
  int c[NEXP];
#pragma unroll
  for (int e = 0; e < NEXP; ++e) c[e] = 0;
  for (int i = t; i < NSLOT; i += 256) {
    int te = tok_e[i];
#pragma unroll
    for (int e = 0; e < NEXP; ++e) c[e] += (te == e) ? 1 : 0;
  }
#pragma unroll
  for (int e = 0; e < NEXP; ++e) h[t * 17 + e] = c[e];
  __syncthreads();
  if (t < NEXP) {
    int s = 0;
    for (int i = 0; i < 256; ++i) s += h[i * 17 + t];
    counts_s[t] = s;
    counts[t] = s;
  }
  __syncthreads();
  if (t == 0) {
    int acc = 0, nt = 0;
    for (int e = 0; e < NEXP; ++e) {
      offsets[e] = acc;
      int cc = counts_s[e];
      for (int m0 = 0; m0 < cc; m0 += 64) { tile_e[nt] = e; tile_m0[nt] = m0; ++nt; }
      acc += cc;
    }
    offsets[NEXP] = acc;
    *ntiles = nt;
  }
}

// ---------------- scatter: one block per expert, deterministic, no atomics ----------------
__global__ void k_scatter2(const int* __restrict__ tok_e, const float* __restrict__ tok_w,
                           const int* __restrict__ offsets, int* __restrict__ token_map,
                           float* __restrict__ gate_w, int* __restrict__ slot_of) {
  int e = blockIdx.x;
  int t = threadIdx.x, lane = t & 63, wv = t >> 6;
  int te[32]; float tw[32];
#pragma unroll
  for (int c = 0; c < 32; ++c) {
    te[c] = tok_e[c * 256 + t];
    tw[c] = tok_w[c * 256 + t];
  }
  __shared__ int wsum[4];
  int run = offsets[e];
  unsigned long long below = (lane == 63) ? 0x7fffffffffffffffull : ((1ull << lane) - 1ull);
#pragma unroll 1
  for (int c = 0; c < 32; ++c) {
    bool f = (te[c] == e);
    unsigned long long m = __ballot(f);
    if (lane == 0) wsum[wv] = __popcll(m);
    __syncthreads();
    int base = run;
    for (int w = 0; w < wv; ++w) base += wsum[w];
    int tot = wsum[0] + wsum[1] + wsum[2] + wsum[3];
    if (f) {
      int i = c * 256 + t;
      int slot = base + __popcll(m & below);
      token_map[slot] = i >> 1;
      gate_w[slot] = tw[c];
      slot_of[i] = slot;
    }
    run += tot;
    __syncthreads();
  }
}

// ---------------- GEMM1: 64x128 tiles, H = gate * silu(X@W1) * (X@W3) ----------------
__global__ __launch_bounds__(256, 3)
void k_gemm1(const unsigned short* __restrict__ Xb, const unsigned short* __restrict__ W1T,
             const unsigned short* __restrict__ W3T, const int* __restrict__ token_map,
             const float* __restrict__ gate_w, const int* __restrict__ ntiles,
             const int* __restrict__ tile_e, const int* __restrict__ tile_m0,
             const int* __restrict__ offsets, const int* __restrict__ counts,
             unsigned short* __restrict__ H) {
  // 960 blocks = 160 m-tiles x 6 n-blocks; 8 consecutive m-tiles share an XCD class.
  int idx = blockIdx.x;
  int xcd = idx & 7, r = idx >> 3;      // r: 0..119
  int g = (r >> 3) * 8 + xcd;           // 0..119
  int mm = r & 7;
  int ty = (g / 6) * 8 + mm;            // 0..159
  if (ty >= *ntiles) return;
  int n0 = (g % 6) * 128;
  int e = tile_e[ty], m0 = tile_m0[ty];
  int base_slot = offsets[e] + m0;
  int cnt = counts[e] - m0; if (cnt > 64) cnt = 64;

  __shared__ unsigned short As[64 * 32];
  __shared__ unsigned short B1s[128 * 32];
  __shared__ unsigned short B3s[128 * 32];

  int t = threadIdx.x;
  int rs = t >> 2, kc = (t & 3) * 8;
  int r0i = base_slot + rs; if (r0i > NSLOT - 1) r0i = NSLOT - 1;
  const unsigned short* ag0 = Xb + (size_t)token_map[r0i] * DDIM + kc;
  const unsigned short* b1g0 = W1T + ((size_t)e * NPAD1 + n0 + rs) * DDIM + kc;
  const unsigned short* b1g1 = b1g0 + (size_t)64 * DDIM;
  const unsigned short* b3g0 = W3T + ((size_t)e * NPAD1 + n0 + rs) * DDIM + kc;
  const unsigned short* b3g1 = b3g0 + (size_t)64 * DDIM;
  unsigned short* asd  = As + t * 8;
  unsigned short* b1d0 = B1s + t * 8;  unsigned short* b1d1 = B1s + 2048 + t * 8;
  unsigned short* b3d0 = B3s + t * 8;  unsigned short* b3d1 = B3s + 2048 + t * 8;

  int lane = t & 63, wv = t >> 6;       // wave wv covers n in [wv*32, wv*32+32)
  int lm = lane & 15, kg = lane >> 4;
  int ao[4], bo[2];
#pragma unroll
  for (int i = 0; i < 4; ++i) ao[i] = (i * 16 + lm) * 32 + kg * 8;
#pragma unroll
  for (int i = 0; i < 2; ++i) bo[i] = (wv * 32 + i * 16 + lm) * 32 + kg * 8;

  f32x4 acc1[4][2], acc3[4][2];
#pragma unroll
  for (int i = 0; i < 4; ++i)
#pragma unroll
    for (int j = 0; j < 2; ++j) { acc1[i][j] = 0.f; acc3[i][j] = 0.f; }

  for (int k0 = 0; k0 < DDIM; k0 += 32) {
    __syncthreads();
    gload_lds16(ag0 + k0, asd);
    gload_lds16(b1g0 + k0, b1d0);
    gload_lds16(b1g1 + k0, b1d1);
    gload_lds16(b3g0 + k0, b3d0);
    gload_lds16(b3g1 + k0, b3d1);
    __syncthreads();
    bf16x8 av[4], b1v[2], b3v[2];
#pragma unroll
    for (int i = 0; i < 4; ++i) av[i] = *(const bf16x8*)(As + ao[i]);
#pragma unroll
    for (int i = 0; i < 2; ++i) {
      b1v[i] = *(const bf16x8*)(B1s + bo[i]);
      b3v[i] = *(const bf16x8*)(B3s + bo[i]);
    }
#pragma unroll
    for (int mi = 0; mi < 4; ++mi)
#pragma unroll
      for (int ni = 0; ni < 2; ++ni) {
        acc1[mi][ni] = __builtin_amdgcn_mfma_f32_16x16x32_bf16(av[mi], b1v[ni], acc1[mi][ni], 0, 0, 0);
        acc3[mi][ni] = __builtin_amdgcn_mfma_f32_16x16x32_bf16(av[mi], b3v[ni], acc3[mi][ni], 0, 0, 0);
      }
  }

  // epilogue: SwiGLU * gate -> bf16 H
#pragma unroll
  for (int mi = 0; mi < 4; ++mi)
#pragma unroll
    for (int rr = 0; rr < 4; ++rr) {
      int orow = mi * 16 + kg * 4 + rr;
      if (orow < cnt) {
        int slot = base_slot + orow;
        float gw = gate_w[slot];
        unsigned short* hrow = H + (size_t)slot * IDIM;
#pragma unroll
        for (int ni = 0; ni < 2; ++ni) {
          int nn = n0 + wv * 32 + ni * 16 + lm;
          if (nn < IDIM) {
            float v1 = acc1[mi][ni][rr];
            float v3 = acc3[mi][ni][rr];
            float h = v1 / (1.f + __expf(-v1)) * v3 * gw;
            hrow[nn] = f2bf(h);
          }
        }
      }
    }
}

// ---------------- GEMM2: 64x128 tiles, O2 = H @ W2 ----------------
__global__ __launch_bounds__(256, 4)
void k_gemm2(const unsigned short* __restrict__ H, const unsigned short* __restrict__ W2T,
             const int* __restrict__ ntiles, const int* __restrict__ tile_e,
             const int* __restrict__ tile_m0, const int* __restrict__ offsets,
             const int* __restrict__ counts, float* __restrict__ O2) {
  // 1280 blocks = 160 m-tiles x 8 n-blocks; 8 consecutive m-tiles per XCD class.
  int idx = blockIdx.x;
  int xcd = idx & 7, r = idx >> 3;      // 0..159
  int g = (r >> 3) * 8 + xcd;           // 0..159
  int mm = r & 7;
  int ty = (g >> 3) * 8 + mm;           // 0..159
  if (ty >= *ntiles) return;
  int n0 = (g & 7) * 128;
  int e = tile_e[ty], m0 = tile_m0[ty];
  int base_slot = offsets[e] + m0;
  int cnt = counts[e] - m0; if (cnt > 64) cnt = 64;

  __shared__ unsigned short As[64 * 32];
  __shared__ unsigned short Bs[128 * 32];

  int t = threadIdx.x;
  int rs = t >> 2, kc = (t & 3) * 8;
  int r0i = base_slot + rs; if (r0i > NSLOT - 1) r0i = NSLOT - 1;
  const unsigned short* ag0 = H + (size_t)r0i * IDIM + kc;
  const unsigned short* bg0 = W2T + ((size_t)e * DDIM + n0 + rs) * IDIM + kc;
  const unsigned short* bg1 = bg0 + (size_t)64 * IDIM;
  unsigned short* asd = As + t * 8;
  unsigned short* bd0 = Bs + t * 8;  unsigned short* bd1 = Bs + 2048 + t * 8;

  int lane = t & 63, wv = t >> 6;
  int lm = lane & 15, kg = lane >> 4;
  int ao[4], bo[2];
#pragma unroll
  for (int i = 0; i < 4; ++i) ao[i] = (i * 16 + lm) * 32 + kg * 8;
#pragma unroll
  for (int i = 0; i < 2; ++i) bo[i] = (wv * 32 + i * 16 + lm) * 32 + kg * 8;

  f32x4 acc[4][2];
#pragma unroll
  for (int i = 0; i < 4; ++i)
#pragma unroll
    for (int j = 0; j < 2; ++j) acc[i][j] = 0.f;

  for (int k0 = 0; k0 < IDIM; k0 += 32) {
    __syncthreads();
    gload_lds16(ag0 + k0, asd);
    gload_lds16(bg0 + k0, bd0);
    gload_lds16(bg1 + k0, bd1);
    __syncthreads();
    bf16x8 av[4], bv[2];
#pragma unroll
    for (int i = 0; i < 4; ++i) av[i] = *(const bf16x8*)(As + ao[i]);
#pragma unroll
    for (int i = 0; i < 2; ++i) bv[i] = *(const bf16x8*)(Bs + bo[i]);
#pragma unroll
    for (int mi = 0; mi < 4; ++mi)
#pragma unroll
      for (int ni = 0; ni < 2; ++ni)
        acc[mi][ni] = __builtin_amdgcn_mfma_f32_16x16x32_bf16(av[mi], bv[ni], acc[mi][ni], 0, 0, 0);
  }

#pragma unroll
  for (int mi = 0; mi < 4; ++mi)
#pragma unroll
    for (int rr = 0; rr < 4; ++rr) {
      int orow = mi * 16 + kg * 4 + rr;
      if (orow < cnt) {
        float* op = O2 + (size_t)(base_slot + orow) * DDIM + n0;
#pragma unroll
        for (int ni = 0; ni < 2; ++ni)
          op[wv * 32 + ni * 16 + lm] = acc[mi][ni][rr];
      }
    }
}

// ---------------- combine: out[t] = O2[slot0] + O2[slot1] ----------------
__global__ void k_combine(const float* __restrict__ O2, const int* __restrict__ slot_of,
                          float* __restrict__ out) {
  int tk = blockIdx.x, tt = threadIdx.x;
  int s0 = slot_of[2 * tk], s1 = slot_of[2 * tk + 1];
  f32x4 a = ((const f32x4*)(O2 + (size_t)s0 * DDIM))[tt];
  f32x4 b = ((const f32x4*)(O2 + (size_t)s1 * DDIM))[tt];
  ((f32x4*)(out + (size_t)tk * DDIM))[tt] = a + b;
}

extern "C" void kernel_launch(void* const* d_in, const int* in_sizes, int n_in,
                              void* d_out, int out_size, void* d_ws, size_t ws_size,
                              hipStream_t stream) {
  const float* x  = (const float*)d_in[0];
  const float* Wg = (const float*)d_in[1];
  const float* W1 = (const float*)d_in[2];
  const float* W2 = (const float*)d_in[3];   // dict order: x, Wg, W1, W2, W3
  const float* W3 = (const float*)d_in[4];
  float* out = (float*)d_out;

  char* ws = (char*)d_ws;
  size_t off = 0;
  unsigned short* Xb = (unsigned short*)(ws + off); off += (size_t)NTOK * DDIM * 2;
  unsigned short* H  = (unsigned short*)(ws + off); off += (size_t)NSLOT * IDIM * 2;
  float* O2 = (float*)(ws + off); off += (size_t)NSLOT * DDIM * 4;
  unsigned short* W1T = (unsigned short*)(ws + off); off += (size_t)NEXP * NPAD1 * DDIM * 2;
  unsigned short* W3T = (unsigned short*)(ws + off); off += (size_t)NEXP * NPAD1 * DDIM * 2;
  unsigned short* W2T = (unsigned short*)(ws + off); off += (size_t)NEXP * DDIM * IDIM * 2;
  int* counts  = (int*)(ws + off); off += 64;
  int* offsets = (int*)(ws + off); off += 128;
  int* ntiles  = (int*)(ws + off); off += 64;
  int* tile_e  = (int*)(ws + off); off += MAXT * 4;
  int* tile_m0 = (int*)(ws + off); off += MAXT * 4;
  int* tok_e   = (int*)(ws + off); off += NSLOT * 4;
  float* tok_w = (float*)(ws + off); off += NSLOT * 4;
  int* token_map = (int*)(ws + off); off += NSLOT * 4;
  float* gate_w  = (float*)(ws + off); off += NSLOT * 4;
  int* slot_of   = (int*)(ws + off); off += NSLOT * 4;

  k_router<<<1024, 256, 0, stream>>>(x, Wg, tok_e, tok_w, Xb);
  k_count_scan<<<1, 256, 0, stream>>>(tok_e, counts, offsets, ntiles, tile_e, tile_m0);
  k_scatter2<<<NEXP, 256, 0, stream>>>(tok_e, tok_w, offsets, token_map, gate_w, slot_of);
  k_wtrans_all<<<8960, 256, 0, stream>>>(W1, W3, W2, W1T, W3T, W2T);
  k_gemm1<<<960, 256, 0, stream>>>(Xb, W1T, W3T, token_map, gate_w, ntiles, tile_e,
                                   tile_m0, offsets, counts, H);
  k_gemm2<<<1280, 256, 0, stream>>>(H, W2T, ntiles, tile_e, tile_m0, offsets, counts, O2);
  k_combine<<<4096, 256, 0, stream>>>(O2, slot_of, out);
}

// Round 6
// 312.104 us; speedup vs baseline: 1.0241x; 1.0241x over previous
//
#include <hip/hip_runtime.h>

#define NTOK 4096
#define DDIM 1024
#define IDIM 704
#define NEXP 16
#define NSLOT 8192
#define MAXT 128
#define NPAD1 768    // IDIM padded to 128 multiple for gemm1 n-dim

typedef __attribute__((ext_vector_type(8))) short bf16x8;
typedef __attribute__((ext_vector_type(4))) float f32x4;
typedef __attribute__((ext_vector_type(4))) unsigned short us4;
typedef __attribute__((ext_vector_type(8))) unsigned short us8;

__device__ __forceinline__ unsigned short f2bf(float f) {
  union { float f; unsigned int u; } v; v.f = f;
  unsigned int r = v.u + 0x7fffu + ((v.u >> 16) & 1u);
  return (unsigned short)(r >> 16);
}

__device__ __forceinline__ void gload_lds16(const void* g, void* l) {
  __builtin_amdgcn_global_load_lds((const __attribute__((address_space(1))) void*)g,
                                   (__attribute__((address_space(3))) void*)l, 16, 0, 0);
}

// ---------------- router + x->bf16 convert, fused; NO atomics ----------------
__global__ void k_router(const float* __restrict__ x, const float* __restrict__ Wg,
                         int* __restrict__ tok_e, float* __restrict__ tok_w,
                         unsigned short* __restrict__ Xb) {
  int lane = threadIdx.x & 63;
  int wv = threadIdx.x >> 6;
  int t = blockIdx.x * 4 + wv;
  const f32x4* xr = (const f32x4*)(x + (size_t)t * DDIM);
  us4* xbr = (us4*)(Xb + (size_t)t * DDIM);
  f32x4 xv[4];
#pragma unroll
  for (int c = 0; c < 4; ++c) {
    xv[c] = xr[c * 64 + lane];
    us4 o;
#pragma unroll
    for (int j = 0; j < 4; ++j) o[j] = f2bf(xv[c][j]);
    xbr[c * 64 + lane] = o;
  }
  float p[NEXP];
#pragma unroll
  for (int e = 0; e < NEXP; ++e) {
    const f32x4* wr = (const f32x4*)(Wg + (size_t)e * DDIM);
    float s = 0.f;
#pragma unroll
    for (int c = 0; c < 4; ++c) {
      f32x4 w4 = wr[c * 64 + lane];
      s += xv[c][0]*w4[0] + xv[c][1]*w4[1] + xv[c][2]*w4[2] + xv[c][3]*w4[3];
    }
    p[e] = s;
  }
#pragma unroll
  for (int off = 32; off >= 1; off >>= 1) {
#pragma unroll
    for (int e = 0; e < NEXP; ++e) p[e] += __shfl_xor(p[e], off);
  }
  int i0 = 0; float b0 = p[0];
#pragma unroll
  for (int e = 1; e < NEXP; ++e) if (p[e] > b0) { b0 = p[e]; i0 = e; }
  int i1 = -1; float b1 = -3.4e38f;
#pragma unroll
  for (int e = 0; e < NEXP; ++e) if (e != i0 && p[e] > b1) { b1 = p[e]; i1 = e; }
  if (lane == 0) {
    float w0 = 1.f / (1.f + __expf(b1 - b0));   // renormalized top-2 softmax weight
    tok_e[2*t] = i0; tok_e[2*t+1] = i1;
    tok_w[2*t] = w0; tok_w[2*t+1] = 1.f - w0;
  }
}

// ---------------- merged count+scan+scatter: 16 blocks, no atomics ----------------
// Every block recomputes the histogram (cheap); block e scatters expert e.
// Block 0 additionally publishes counts/offsets/ntiles/tile lists.
__global__ void k_scan_scatter(const int* __restrict__ tok_e, const float* __restrict__ tok_w,
                               int* __restrict__ counts, int* __restrict__ offsets,
                               int* __restrict__ ntiles, int* __restrict__ tile_e,
                               int* __restrict__ tile_m0, int* __restrict__ token_map,
                               float* __restrict__ gate_w, int* __restrict__ slot_of) {
  int eb = blockIdx.x;
  int t = threadIdx.x, lane = t & 63, wv = t >> 6;
  __shared__ int h[256 * 17];
  __shared__ int counts_s[NEXP];
  __shared__ int wsum[4];
  int te[32]; float tw[32];
#pragma unroll
  for (int c = 0; c < 32; ++c) {
    te[c] = tok_e[c * 256 + t];
    tw[c] = tok_w[c * 256 + t];
  }
  int c[NEXP];
#pragma unroll
  for (int e = 0; e < NEXP; ++e) c[e] = 0;
#pragma unroll
  for (int i = 0; i < 32; ++i) {
#pragma unroll
    for (int e = 0; e < NEXP; ++e) c[e] += (te[i] == e) ? 1 : 0;
  }
#pragma unroll
  for (int e = 0; e < NEXP; ++e) h[t * 17 + e] = c[e];
  __syncthreads();
  if (t < NEXP) {
    int s = 0;
    for (int i = 0; i < 256; ++i) s += h[i * 17 + t];
    counts_s[t] = s;
    if (eb == 0) counts[t] = s;
  }
  __syncthreads();
  int off_e = 0;
#pragma unroll
  for (int e = 0; e < NEXP; ++e) off_e += (e < eb) ? counts_s[e] : 0;
  if (eb == 0 && t == 0) {
    int acc = 0, nt = 0;
    for (int e = 0; e < NEXP; ++e) {
      offsets[e] = acc;
      int cc = counts_s[e];
      for (int m0 = 0; m0 < cc; m0 += 128) { tile_e[nt] = e; tile_m0[nt] = m0; ++nt; }
      acc += cc;
    }
    offsets[NEXP] = acc;
    *ntiles = nt;
  }
  // scatter for expert eb (deterministic ballot-rank)
  int run = off_e;
  unsigned long long below = (lane == 63) ? 0x7fffffffffffffffull : ((1ull << lane) - 1ull);
#pragma unroll 1
  for (int cc = 0; cc < 32; ++cc) {
    bool f = (te[cc] == eb);
    unsigned long long m = __ballot(f);
    if (lane == 0) wsum[wv] = __popcll(m);
    __syncthreads();
    int base = run;
    for (int w = 0; w < wv; ++w) base += wsum[w];
    int tot = wsum[0] + wsum[1] + wsum[2] + wsum[3];
    if (f) {
      int i = cc * 256 + t;
      int slot = base + __popcll(m & below);
      token_map[slot] = i >> 1;
      gate_w[slot] = tw[cc];
      slot_of[i] = slot;
    }
    run += tot;
    __syncthreads();
  }
}

// ---------------- merged weight transpose+convert; 2 n-tiles per block ----------------
// [e][k][n] fp32 -> [e][npad][k] bf16, 64x64 sub-tiles, XOR-swizzled LDS.
__global__ void k_wtrans_all(const float* __restrict__ W1, const float* __restrict__ W3,
                             const float* __restrict__ W2, unsigned short* __restrict__ W1T,
                             unsigned short* __restrict__ W3T, unsigned short* __restrict__ W2T) {
  int b = blockIdx.x;
  const float* src; unsigned short* dst;
  int ksz, nsz, kx, np, e;
  if (b < 3072) {                 // W1: 0..1535, W3: 1536..3071 (16 k-tiles x 6 n-pairs x 16 e)
    int which = (b >= 1536) ? 1 : 0;
    int tb = b - which * 1536;
    kx = tb & 15; int rest = tb >> 4; np = rest % 6; e = rest / 6;
    ksz = DDIM; nsz = IDIM;
    src = (which ? W3 : W1) + (size_t)e * DDIM * IDIM;
    dst = (which ? W3T : W1T) + (size_t)e * NPAD1 * DDIM;
  } else {                        // W2: 11 k-tiles x 8 n-pairs x 16 e
    int tb = b - 3072;
    kx = tb % 11; int rest = tb / 11; np = rest & 7; e = rest >> 3;
    ksz = IDIM; nsz = DDIM;
    src = W2 + (size_t)e * IDIM * DDIM;
    dst = W2T + (size_t)e * DDIM * IDIM;
  }
  int k0 = kx * 64;
  __shared__ unsigned short lds[64 * 64];
  int t = threadIdx.x;
#pragma unroll
  for (int p = 0; p < 2; ++p) {
    int n0 = np * 128 + p * 64;
    if (p) __syncthreads();
    if (n0 >= nsz) {              // n-padding rows (only last pass of W1/W3): zeros
      int nr = t >> 3, kc0 = (t & 7) * 8;
      us8 z = (us8)(unsigned short)0;
#pragma unroll
      for (int q = 0; q < 2; ++q)
        *(us8*)(dst + (size_t)(n0 + nr + q * 32) * ksz + k0 + kc0) = z;
      continue;
    }
    int kr4 = (t >> 4) * 4, nc4 = (t & 15) * 4;
    f32x4 v[4];
#pragma unroll
    for (int j = 0; j < 4; ++j)
      v[j] = *(const f32x4*)(src + (size_t)(k0 + kr4 + j) * nsz + n0 + nc4);
    int c8 = kr4 >> 3, half = (kr4 >> 2) & 1;
#pragma unroll
    for (int i = 0; i < 4; ++i) {
      us4 o;
#pragma unroll
      for (int j = 0; j < 4; ++j) o[j] = f2bf(v[j][i]);
      int row = nc4 + i;
      int addr = row * 64 + ((c8 ^ ((row >> 2) & 7)) << 3) + half * 4;
      *(us4*)(lds + addr) = o;
    }
    __syncthreads();
    int nr = t >> 3, kc8 = t & 7;
#pragma unroll
    for (int q = 0; q < 2; ++q) {
      int row = nr + q * 32;
      us8 o = *(const us8*)(lds + row * 64 + ((kc8 ^ ((row >> 2) & 7)) << 3));
      *(us8*)(dst + (size_t)(n0 + row) * ksz + k0 + kc8 * 8) = o;
    }
  }
}

// ---------------- GEMM1: 128x128, double-buffered LDS, XCD-swizzled ----------------
__global__ __launch_bounds__(256, 2)
void k_gemm1(const unsigned short* __restrict__ Xb, const unsigned short* __restrict__ W1T,
             const unsigned short* __restrict__ W3T, const int* __restrict__ token_map,
             const float* __restrict__ gate_w, const int* __restrict__ ntiles,
             const int* __restrict__ tile_e, const int* __restrict__ tile_m0,
             const int* __restrict__ offsets, const int* __restrict__ counts,
             unsigned short* __restrict__ H) {
  // 480 blocks = 80 m-tiles x 6 n-blocks; 4 consecutive m-tiles share an XCD class.
  int idx = blockIdx.x;
  int xcd = idx & 7, r = idx >> 3;
  int g = (r >> 2) * 8 + xcd;       // 0..119
  int mm = r & 3;
  int ty = (g / 6) * 4 + mm;        // 0..79
  if (ty >= *ntiles) return;
  int n0 = (g % 6) * 128;
  int e = tile_e[ty], m0 = tile_m0[ty];
  int base_slot = offsets[e] + m0;
  int cnt = counts[e] - m0; if (cnt > 128) cnt = 128;

  __shared__ unsigned short As[2][128 * 32];
  __shared__ unsigned short B1s[2][128 * 32];
  __shared__ unsigned short B3s[2][128 * 32];

  int t = threadIdx.x;
  int row = t >> 2, kc = (t & 3) * 8;
  int r0i = base_slot + row;      if (r0i > NSLOT - 1) r0i = NSLOT - 1;
  int r1i = base_slot + 64 + row; if (r1i > NSLOT - 1) r1i = NSLOT - 1;
  const unsigned short* ag0 = Xb + (size_t)token_map[r0i] * DDIM + kc;
  const unsigned short* ag1 = Xb + (size_t)token_map[r1i] * DDIM + kc;
  const unsigned short* b1g0 = W1T + ((size_t)e * NPAD1 + n0 + row) * DDIM + kc;
  const unsigned short* b1g1 = b1g0 + (size_t)64 * DDIM;
  const unsigned short* b3g0 = W3T + ((size_t)e * NPAD1 + n0 + row) * DDIM + kc;
  const unsigned short* b3g1 = b3g0 + (size_t)64 * DDIM;
  int d0 = t * 8, d1 = 2048 + t * 8;

  int lane = t & 63, wv = t >> 6;
  int wm = (wv >> 1) * 64, wn = (wv & 1) * 64;
  int lm = lane & 15, kg = lane >> 4;
  int ao[4], bo[4];
#pragma unroll
  for (int i = 0; i < 4; ++i) {
    ao[i] = (wm + i * 16 + lm) * 32 + kg * 8;
    bo[i] = (wn + i * 16 + lm) * 32 + kg * 8;
  }

  f32x4 acc1[4][4], acc3[4][4];
#pragma unroll
  for (int i = 0; i < 4; ++i)
#pragma unroll
    for (int j = 0; j < 4; ++j) { acc1[i][j] = 0.f; acc3[i][j] = 0.f; }

  // prologue: stage tile 0
  gload_lds16(ag0, As[0] + d0);
  gload_lds16(ag1, As[0] + d1);
  gload_lds16(b1g0, B1s[0] + d0);
  gload_lds16(b1g1, B1s[0] + d1);
  gload_lds16(b3g0, B3s[0] + d0);
  gload_lds16(b3g1, B3s[0] + d1);

  for (int k0 = 0; k0 < DDIM; k0 += 32) {
    int cur = (k0 >> 5) & 1;
    __syncthreads();                       // tile k0 resident (vmcnt drain)
    if (k0 + 32 < DDIM) {                  // prefetch tile k0+32 into other stage
      int nx = cur ^ 1, kn = k0 + 32;
      gload_lds16(ag0 + kn, As[nx] + d0);
      gload_lds16(ag1 + kn, As[nx] + d1);
      gload_lds16(b1g0 + kn, B1s[nx] + d0);
      gload_lds16(b1g1 + kn, B1s[nx] + d1);
      gload_lds16(b3g0 + kn, B3s[nx] + d0);
      gload_lds16(b3g1 + kn, B3s[nx] + d1);
    }
    bf16x8 av[4], b1v[4], b3v[4];
#pragma unroll
    for (int i = 0; i < 4; ++i) {
      av[i]  = *(const bf16x8*)(As[cur] + ao[i]);
      b1v[i] = *(const bf16x8*)(B1s[cur] + bo[i]);
      b3v[i] = *(const bf16x8*)(B3s[cur] + bo[i]);
    }
#pragma unroll
    for (int mi = 0; mi < 4; ++mi)
#pragma unroll
      for (int ni = 0; ni < 4; ++ni) {
        acc1[mi][ni] = __builtin_amdgcn_mfma_f32_16x16x32_bf16(av[mi], b1v[ni], acc1[mi][ni], 0, 0, 0);
        acc3[mi][ni] = __builtin_amdgcn_mfma_f32_16x16x32_bf16(av[mi], b3v[ni], acc3[mi][ni], 0, 0, 0);
      }
  }

  // epilogue: SwiGLU * gate -> bf16 H
#pragma unroll
  for (int mi = 0; mi < 4; ++mi)
#pragma unroll
    for (int rr = 0; rr < 4; ++rr) {
      int orow = wm + mi * 16 + kg * 4 + rr;
      if (orow < cnt) {
        int slot = base_slot + orow;
        float gw = gate_w[slot];
        unsigned short* hrow = H + (size_t)slot * IDIM;
#pragma unroll
        for (int ni = 0; ni < 4; ++ni) {
          int nn = n0 + wn + ni * 16 + lm;
          if (nn < IDIM) {
            float v1 = acc1[mi][ni][rr];
            float v3 = acc3[mi][ni][rr];
            float h = v1 / (1.f + __expf(-v1)) * v3 * gw;
            hrow[nn] = f2bf(h);
          }
        }
      }
    }
}

// ---------------- GEMM2: 128x128, double-buffered LDS, XCD-swizzled ----------------
__global__ __launch_bounds__(256, 3)
void k_gemm2(const unsigned short* __restrict__ H, const unsigned short* __restrict__ W2T,
             const int* __restrict__ ntiles, const int* __restrict__ tile_e,
             const int* __restrict__ tile_m0, const int* __restrict__ offsets,
             const int* __restrict__ counts, float* __restrict__ O2) {
  // 640 blocks = 80 m-tiles x 8 n-blocks.
  int idx = blockIdx.x;
  int xcd = idx & 7, r = idx >> 3;
  int g = (r >> 2) * 8 + xcd;       // 0..159
  int mm = r & 3;
  int ty = (g >> 3) * 4 + mm;       // 0..79
  if (ty >= *ntiles) return;
  int n0 = (g & 7) * 128;
  int e = tile_e[ty], m0 = tile_m0[ty];
  int base_slot = offsets[e] + m0;
  int cnt = counts[e] - m0; if (cnt > 128) cnt = 128;

  __shared__ unsigned short As[2][128 * 32];
  __shared__ unsigned short Bs[2][128 * 32];

  int t = threadIdx.x;
  int row = t >> 2, kc = (t & 3) * 8;
  int r0i = base_slot + row;      if (r0i > NSLOT - 1) r0i = NSLOT - 1;
  int r1i = base_slot + 64 + row; if (r1i > NSLOT - 1) r1i = NSLOT - 1;
  const unsigned short* ag0 = H + (size_t)r0i * IDIM + kc;
  const unsigned short* ag1 = H + (size_t)r1i * IDIM + kc;
  const unsigned short* bg0 = W2T + ((size_t)e * DDIM + n0 + row) * IDIM + kc;
  const unsigned short* bg1 = bg0 + (size_t)64 * IDIM;
  int d0 = t * 8, d1 = 2048 + t * 8;

  int lane = t & 63, wv = t >> 6;
  int wm = (wv >> 1) * 64, wn = (wv & 1) * 64;
  int lm = lane & 15, kg = lane >> 4;
  int ao[4], bo[4];
#pragma unroll
  for (int i = 0; i < 4; ++i) {
    ao[i] = (wm + i * 16 + lm) * 32 + kg * 8;
    bo[i] = (wn + i * 16 + lm) * 32 + kg * 8;
  }

  f32x4 acc[4][4];
#pragma unroll
  for (int i = 0; i < 4; ++i)
#pragma unroll
    for (int j = 0; j < 4; ++j) acc[i][j] = 0.f;

  gload_lds16(ag0, As[0] + d0);
  gload_lds16(ag1, As[0] + d1);
  gload_lds16(bg0, Bs[0] + d0);
  gload_lds16(bg1, Bs[0] + d1);

  for (int k0 = 0; k0 < IDIM; k0 += 32) {
    int cur = (k0 >> 5) & 1;
    __syncthreads();
    if (k0 + 32 < IDIM) {
      int nx = cur ^ 1, kn = k0 + 32;
      gload_lds16(ag0 + kn, As[nx] + d0);
      gload_lds16(ag1 + kn, As[nx] + d1);
      gload_lds16(bg0 + kn, Bs[nx] + d0);
      gload_lds16(bg1 + kn, Bs[nx] + d1);
    }
    bf16x8 av[4], bv[4];
#pragma unroll
    for (int i = 0; i < 4; ++i) {
      av[i] = *(const bf16x8*)(As[cur] + ao[i]);
      bv[i] = *(const bf16x8*)(Bs[cur] + bo[i]);
    }
#pragma unroll
    for (int mi = 0; mi < 4; ++mi)
#pragma unroll
      for (int ni = 0; ni < 4; ++ni)
        acc[mi][ni] = __builtin_amdgcn_mfma_f32_16x16x32_bf16(av[mi], bv[ni], acc[mi][ni], 0, 0, 0);
  }

#pragma unroll
  for (int mi = 0; mi < 4; ++mi)
#pragma unroll
    for (int rr = 0; rr < 4; ++rr) {
      int orow = wm + mi * 16 + kg * 4 + rr;
      if (orow < cnt) {
        float* op = O2 + (size_t)(base_slot + orow) * DDIM + n0;
#pragma unroll
        for (int ni = 0; ni < 4; ++ni)
          op[wn + ni * 16 + lm] = acc[mi][ni][rr];
      }
    }
}

// ---------------- combine: out[t] = O2[slot0] + O2[slot1] ----------------
__global__ void k_combine(const float* __restrict__ O2, const int* __restrict__ slot_of,
                          float* __restrict__ out) {
  int tk = blockIdx.x, tt = threadIdx.x;
  int s0 = slot_of[2 * tk], s1 = slot_of[2 * tk + 1];
  f32x4 a = ((const f32x4*)(O2 + (size_t)s0 * DDIM))[tt];
  f32x4 b = ((const f32x4*)(O2 + (size_t)s1 * DDIM))[tt];
  ((f32x4*)(out + (size_t)tk * DDIM))[tt] = a + b;
}

extern "C" void kernel_launch(void* const* d_in, const int* in_sizes, int n_in,
                              void* d_out, int out_size, void* d_ws, size_t ws_size,
                              hipStream_t stream) {
  const float* x  = (const float*)d_in[0];
  const float* Wg = (const float*)d_in[1];
  const float* W1 = (const float*)d_in[2];
  const float* W2 = (const float*)d_in[3];   // dict order: x, Wg, W1, W2, W3
  const float* W3 = (const float*)d_in[4];
  float* out = (float*)d_out;

  char* ws = (char*)d_ws;
  size_t off = 0;
  unsigned short* Xb = (unsigned short*)(ws + off); off += (size_t)NTOK * DDIM * 2;
  unsigned short* H  = (unsigned short*)(ws + off); off += (size_t)NSLOT * IDIM * 2;
  float* O2 = (float*)(ws + off); off += (size_t)NSLOT * DDIM * 4;
  unsigned short* W1T = (unsigned short*)(ws + off); off += (size_t)NEXP * NPAD1 * DDIM * 2;
  unsigned short* W3T = (unsigned short*)(ws + off); off += (size_t)NEXP * NPAD1 * DDIM * 2;
  unsigned short* W2T = (unsigned short*)(ws + off); off += (size_t)NEXP * DDIM * IDIM * 2;
  int* counts  = (int*)(ws + off); off += 64;
  int* offsets = (int*)(ws + off); off += 128;
  int* ntiles  = (int*)(ws + off); off += 64;
  int* tile_e  = (int*)(ws + off); off += MAXT * 4;
  int* tile_m0 = (int*)(ws + off); off += MAXT * 4;
  int* tok_e   = (int*)(ws + off); off += NSLOT * 4;
  float* tok_w = (float*)(ws + off); off += NSLOT * 4;
  int* token_map = (int*)(ws + off); off += NSLOT * 4;
  float* gate_w  = (float*)(ws + off); off += NSLOT * 4;
  int* slot_of   = (int*)(ws + off); off += NSLOT * 4;

  k_router<<<1024, 256, 0, stream>>>(x, Wg, tok_e, tok_w, Xb);
  k_scan_scatter<<<NEXP, 256, 0, stream>>>(tok_e, tok_w, counts, offsets, ntiles,
                                           tile_e, tile_m0, token_map, gate_w, slot_of);
  k_wtrans_all<<<4480, 256, 0, stream>>>(W1, W3, W2, W1T, W3T, W2T);
  k_gemm1<<<480, 256, 0, stream>>>(Xb, W1T, W3T, token_map, gate_w, ntiles, tile_e,
                                   tile_m0, offsets, counts, H);
  k_gemm2<<<640, 256, 0, stream>>>(H, W2T, ntiles, tile_e, tile_m0, offsets, counts, O2);
  k_combine<<<4096, 256, 0, stream>>>(O2, slot_of, out);
}

// Round 7
// 301.927 us; speedup vs baseline: 1.0586x; 1.0337x over previous
//
#include <hip/hip_runtime.h>

#define NTOK 4096
#define DDIM 1024
#define IDIM 704
#define NEXP 16
#define NSLOT 8192
#define MAXT 128
#define NPAD1 768    // IDIM padded to 128 multiple for gemm1 n-dim
#define WTBLK 4480   // wtrans blocks: W1 1536 + W3 1536 + W2 1408

typedef __attribute__((ext_vector_type(8))) short bf16x8;
typedef __attribute__((ext_vector_type(4))) float f32x4;
typedef __attribute__((ext_vector_type(4))) unsigned short us4;
typedef __attribute__((ext_vector_type(8))) unsigned short us8;

__device__ __forceinline__ unsigned short f2bf(float f) {
  union { float f; unsigned int u; } v; v.f = f;
  unsigned int r = v.u + 0x7fffu + ((v.u >> 16) & 1u);
  return (unsigned short)(r >> 16);
}

__device__ __forceinline__ float bf2f(unsigned short b) {
  union { unsigned int u; float f; } v; v.u = ((unsigned int)b) << 16;
  return v.f;
}

__device__ __forceinline__ void gload_lds16(const void* g, void* l) {
  __builtin_amdgcn_global_load_lds((const __attribute__((address_space(1))) void*)g,
                                   (__attribute__((address_space(3))) void*)l, 16, 0, 0);
}

// ---------------- front: weight transpose (blocks 0..4479) + router (4480..5503) ----------------
// wtrans: [e][k][n] fp32 -> [e][npad][k] bf16; one 64k x 128n region per block,
// all 8 global loads in flight before first use (latency hiding), 2x 64x64
// XOR-swizzled LDS buffers, single barrier.
// router: wave per token; top-2 softmax weights + x->bf16 convert fused.
__global__ void k_front(const float* __restrict__ x, const float* __restrict__ Wg,
                        const float* __restrict__ W1, const float* __restrict__ W3,
                        const float* __restrict__ W2, int* __restrict__ tok_e,
                        float* __restrict__ tok_w, unsigned short* __restrict__ Xb,
                        unsigned short* __restrict__ W1T, unsigned short* __restrict__ W3T,
                        unsigned short* __restrict__ W2T) {
  int b = blockIdx.x;
  if (b < WTBLK) {
    __shared__ unsigned short lds[2][64 * 64];
    const float* src; unsigned short* dst;
    int ksz, nsz, kx, np, e;
    if (b < 3072) {               // W1: 0..1535, W3: 1536..3071 (16 k x 6 npair x 16 e)
      int which = (b >= 1536) ? 1 : 0;
      int tb = b - which * 1536;
      kx = tb & 15; int rest = tb >> 4; np = rest % 6; e = rest / 6;
      ksz = DDIM; nsz = IDIM;
      src = (which ? W3 : W1) + (size_t)e * DDIM * IDIM;
      dst = (which ? W3T : W1T) + (size_t)e * NPAD1 * DDIM;
    } else {                      // W2: 11 k x 8 npair x 16 e
      int tb = b - 3072;
      kx = tb % 11; int rest = tb / 11; np = rest & 7; e = rest >> 3;
      ksz = IDIM; nsz = DDIM;
      src = W2 + (size_t)e * IDIM * DDIM;
      dst = W2T + (size_t)e * DDIM * IDIM;
    }
    int k0 = kx * 64;
    int t = threadIdx.x;
    int kr4 = (t >> 4) * 4, nc4 = (t & 15) * 4;
    int n0a = np * 128, n0b = n0a + 64;
    bool bvalid = n0b < nsz;      // half B padding only on last W1/W3 n-pair
    // issue all 8 loads before any conversion
    f32x4 v0[4], v1[4];
#pragma unroll
    for (int j = 0; j < 4; ++j)
      v0[j] = *(const f32x4*)(src + (size_t)(k0 + kr4 + j) * nsz + n0a + nc4);
    if (bvalid) {
#pragma unroll
      for (int j = 0; j < 4; ++j)
        v1[j] = *(const f32x4*)(src + (size_t)(k0 + kr4 + j) * nsz + n0b + nc4);
    }
    int c8 = kr4 >> 3, half = (kr4 >> 2) & 1;
#pragma unroll
    for (int i = 0; i < 4; ++i) {
      int row = nc4 + i;
      int addr = row * 64 + ((c8 ^ ((row >> 2) & 7)) << 3) + half * 4;
      us4 o0;
#pragma unroll
      for (int j = 0; j < 4; ++j) o0[j] = f2bf(v0[j][i]);
      *(us4*)(lds[0] + addr) = o0;
      if (bvalid) {
        us4 o1;
#pragma unroll
        for (int j = 0; j < 4; ++j) o1[j] = f2bf(v1[j][i]);
        *(us4*)(lds[1] + addr) = o1;
      }
    }
    __syncthreads();
    int nr = t >> 3, kc8 = t & 7;
#pragma unroll
    for (int q = 0; q < 2; ++q) {
      int row = nr + q * 32;
      us8 oA = *(const us8*)(lds[0] + row * 64 + ((kc8 ^ ((row >> 2) & 7)) << 3));
      *(us8*)(dst + (size_t)(n0a + row) * ksz + k0 + kc8 * 8) = oA;
      us8 oB = bvalid ? *(const us8*)(lds[1] + row * 64 + ((kc8 ^ ((row >> 2) & 7)) << 3))
                      : (us8)(unsigned short)0;
      *(us8*)(dst + (size_t)(n0b + row) * ksz + k0 + kc8 * 8) = oB;
    }
    return;
  }
  // ---- router ----
  int rb = b - WTBLK;
  int lane = threadIdx.x & 63;
  int wv = threadIdx.x >> 6;
  int tk = rb * 4 + wv;
  const f32x4* xr = (const f32x4*)(x + (size_t)tk * DDIM);
  us4* xbr = (us4*)(Xb + (size_t)tk * DDIM);
  f32x4 xv[4];
#pragma unroll
  for (int c = 0; c < 4; ++c) {
    xv[c] = xr[c * 64 + lane];
    us4 o;
#pragma unroll
    for (int j = 0; j < 4; ++j) o[j] = f2bf(xv[c][j]);
    xbr[c * 64 + lane] = o;
  }
  float p[NEXP];
#pragma unroll
  for (int e = 0; e < NEXP; ++e) {
    const f32x4* wr = (const f32x4*)(Wg + (size_t)e * DDIM);
    float s = 0.f;
#pragma unroll
    for (int c = 0; c < 4; ++c) {
      f32x4 w4 = wr[c * 64 + lane];
      s += xv[c][0]*w4[0] + xv[c][1]*w4[1] + xv[c][2]*w4[2] + xv[c][3]*w4[3];
    }
    p[e] = s;
  }
#pragma unroll
  for (int off = 32; off >= 1; off >>= 1) {
#pragma unroll
    for (int e = 0; e < NEXP; ++e) p[e] += __shfl_xor(p[e], off);
  }
  int i0 = 0; float b0 = p[0];
#pragma unroll
  for (int e = 1; e < NEXP; ++e) if (p[e] > b0) { b0 = p[e]; i0 = e; }
  int i1 = -1; float b1 = -3.4e38f;
#pragma unroll
  for (int e = 0; e < NEXP; ++e) if (e != i0 && p[e] > b1) { b1 = p[e]; i1 = e; }
  if (lane == 0) {
    float w0 = 1.f / (1.f + __expf(b1 - b0));   // renormalized top-2 softmax weight
    tok_e[2*tk] = i0; tok_e[2*tk+1] = i1;
    tok_w[2*tk] = w0; tok_w[2*tk+1] = 1.f - w0;
  }
}

// ---------------- merged count+scan+scatter: 16 blocks, no atomics ----------------
__global__ void k_scan_scatter(const int* __restrict__ tok_e, const float* __restrict__ tok_w,
                               int* __restrict__ counts, int* __restrict__ offsets,
                               int* __restrict__ ntiles, int* __restrict__ tile_e,
                               int* __restrict__ tile_m0, int* __restrict__ token_map,
                               float* __restrict__ gate_w, int* __restrict__ slot_of) {
  int eb = blockIdx.x;
  int t = threadIdx.x, lane = t & 63, wv = t >> 6;
  __shared__ int h[256 * 17];
  __shared__ int counts_s[NEXP];
  __shared__ int wsum[4];
  int te[32]; float tw[32];
#pragma unroll
  for (int c = 0; c < 32; ++c) {
    te[c] = tok_e[c * 256 + t];
    tw[c] = tok_w[c * 256 + t];
  }
  int c[NEXP];
#pragma unroll
  for (int e = 0; e < NEXP; ++e) c[e] = 0;
#pragma unroll
  for (int i = 0; i < 32; ++i) {
#pragma unroll
    for (int e = 0; e < NEXP; ++e) c[e] += (te[i] == e) ? 1 : 0;
  }
#pragma unroll
  for (int e = 0; e < NEXP; ++e) h[t * 17 + e] = c[e];
  __syncthreads();
  if (t < NEXP) {
    int s = 0;
    for (int i = 0; i < 256; ++i) s += h[i * 17 + t];
    counts_s[t] = s;
    if (eb == 0) counts[t] = s;
  }
  __syncthreads();
  int off_e = 0;
#pragma unroll
  for (int e = 0; e < NEXP; ++e) off_e += (e < eb) ? counts_s[e] : 0;
  if (eb == 0 && t == 0) {
    int acc = 0, nt = 0;
    for (int e = 0; e < NEXP; ++e) {
      offsets[e] = acc;
      int cc = counts_s[e];
      for (int m0 = 0; m0 < cc; m0 += 128) { tile_e[nt] = e; tile_m0[nt] = m0; ++nt; }
      acc += cc;
    }
    offsets[NEXP] = acc;
    *ntiles = nt;
  }
  int run = off_e;
  unsigned long long below = (lane == 63) ? 0x7fffffffffffffffull : ((1ull << lane) - 1ull);
#pragma unroll 1
  for (int cc = 0; cc < 32; ++cc) {
    bool f = (te[cc] == eb);
    unsigned long long m = __ballot(f);
    if (lane == 0) wsum[wv] = __popcll(m);
    __syncthreads();
    int base = run;
    for (int w = 0; w < wv; ++w) base += wsum[w];
    int tot = wsum[0] + wsum[1] + wsum[2] + wsum[3];
    if (f) {
      int i = cc * 256 + t;
      int slot = base + __popcll(m & below);
      token_map[slot] = i >> 1;
      gate_w[slot] = tw[cc];
      slot_of[i] = slot;
    }
    run += tot;
    __syncthreads();
  }
}

// ---------------- GEMM1: 128x128, double-buffered LDS, XCD-swizzled ----------------
__global__ __launch_bounds__(256, 2)
void k_gemm1(const unsigned short* __restrict__ Xb, const unsigned short* __restrict__ W1T,
             const unsigned short* __restrict__ W3T, const int* __restrict__ token_map,
             const float* __restrict__ gate_w, const int* __restrict__ ntiles,
             const int* __restrict__ tile_e, const int* __restrict__ tile_m0,
             const int* __restrict__ offsets, const int* __restrict__ counts,
             unsigned short* __restrict__ H) {
  int idx = blockIdx.x;
  int xcd = idx & 7, r = idx >> 3;
  int g = (r >> 2) * 8 + xcd;       // 0..119
  int mm = r & 3;
  int ty = (g / 6) * 4 + mm;        // 0..79
  if (ty >= *ntiles) return;
  int n0 = (g % 6) * 128;
  int e = tile_e[ty], m0 = tile_m0[ty];
  int base_slot = offsets[e] + m0;
  int cnt = counts[e] - m0; if (cnt > 128) cnt = 128;

  __shared__ unsigned short As[2][128 * 32];
  __shared__ unsigned short B1s[2][128 * 32];
  __shared__ unsigned short B3s[2][128 * 32];

  int t = threadIdx.x;
  int row = t >> 2, kc = (t & 3) * 8;
  int r0i = base_slot + row;      if (r0i > NSLOT - 1) r0i = NSLOT - 1;
  int r1i = base_slot + 64 + row; if (r1i > NSLOT - 1) r1i = NSLOT - 1;
  const unsigned short* ag0 = Xb + (size_t)token_map[r0i] * DDIM + kc;
  const unsigned short* ag1 = Xb + (size_t)token_map[r1i] * DDIM + kc;
  const unsigned short* b1g0 = W1T + ((size_t)e * NPAD1 + n0 + row) * DDIM + kc;
  const unsigned short* b1g1 = b1g0 + (size_t)64 * DDIM;
  const unsigned short* b3g0 = W3T + ((size_t)e * NPAD1 + n0 + row) * DDIM + kc;
  const unsigned short* b3g1 = b3g0 + (size_t)64 * DDIM;
  int d0 = t * 8, d1 = 2048 + t * 8;

  int lane = t & 63, wv = t >> 6;
  int wm = (wv >> 1) * 64, wn = (wv & 1) * 64;
  int lm = lane & 15, kg = lane >> 4;
  int ao[4], bo[4];
#pragma unroll
  for (int i = 0; i < 4; ++i) {
    ao[i] = (wm + i * 16 + lm) * 32 + kg * 8;
    bo[i] = (wn + i * 16 + lm) * 32 + kg * 8;
  }

  f32x4 acc1[4][4], acc3[4][4];
#pragma unroll
  for (int i = 0; i < 4; ++i)
#pragma unroll
    for (int j = 0; j < 4; ++j) { acc1[i][j] = 0.f; acc3[i][j] = 0.f; }

  gload_lds16(ag0, As[0] + d0);
  gload_lds16(ag1, As[0] + d1);
  gload_lds16(b1g0, B1s[0] + d0);
  gload_lds16(b1g1, B1s[0] + d1);
  gload_lds16(b3g0, B3s[0] + d0);
  gload_lds16(b3g1, B3s[0] + d1);

  for (int k0 = 0; k0 < DDIM; k0 += 32) {
    int cur = (k0 >> 5) & 1;
    __syncthreads();
    if (k0 + 32 < DDIM) {
      int nx = cur ^ 1, kn = k0 + 32;
      gload_lds16(ag0 + kn, As[nx] + d0);
      gload_lds16(ag1 + kn, As[nx] + d1);
      gload_lds16(b1g0 + kn, B1s[nx] + d0);
      gload_lds16(b1g1 + kn, B1s[nx] + d1);
      gload_lds16(b3g0 + kn, B3s[nx] + d0);
      gload_lds16(b3g1 + kn, B3s[nx] + d1);
    }
    bf16x8 av[4], b1v[4], b3v[4];
#pragma unroll
    for (int i = 0; i < 4; ++i) {
      av[i]  = *(const bf16x8*)(As[cur] + ao[i]);
      b1v[i] = *(const bf16x8*)(B1s[cur] + bo[i]);
      b3v[i] = *(const bf16x8*)(B3s[cur] + bo[i]);
    }
#pragma unroll
    for (int mi = 0; mi < 4; ++mi)
#pragma unroll
      for (int ni = 0; ni < 4; ++ni) {
        acc1[mi][ni] = __builtin_amdgcn_mfma_f32_16x16x32_bf16(av[mi], b1v[ni], acc1[mi][ni], 0, 0, 0);
        acc3[mi][ni] = __builtin_amdgcn_mfma_f32_16x16x32_bf16(av[mi], b3v[ni], acc3[mi][ni], 0, 0, 0);
      }
  }

#pragma unroll
  for (int mi = 0; mi < 4; ++mi)
#pragma unroll
    for (int rr = 0; rr < 4; ++rr) {
      int orow = wm + mi * 16 + kg * 4 + rr;
      if (orow < cnt) {
        int slot = base_slot + orow;
        float gw = gate_w[slot];
        unsigned short* hrow = H + (size_t)slot * IDIM;
#pragma unroll
        for (int ni = 0; ni < 4; ++ni) {
          int nn = n0 + wn + ni * 16 + lm;
          if (nn < IDIM) {
            float v1 = acc1[mi][ni][rr];
            float v3 = acc3[mi][ni][rr];
            float hh = v1 / (1.f + __expf(-v1)) * v3 * gw;
            hrow[nn] = f2bf(hh);
          }
        }
      }
    }
}

// ---------------- GEMM2: 128x128, double-buffered LDS, bf16 output ----------------
__global__ __launch_bounds__(256, 3)
void k_gemm2(const unsigned short* __restrict__ H, const unsigned short* __restrict__ W2T,
             const int* __restrict__ ntiles, const int* __restrict__ tile_e,
             const int* __restrict__ tile_m0, const int* __restrict__ offsets,
             const int* __restrict__ counts, unsigned short* __restrict__ O2) {
  int idx = blockIdx.x;
  int xcd = idx & 7, r = idx >> 3;
  int g = (r >> 2) * 8 + xcd;       // 0..159
  int mm = r & 3;
  int ty = (g >> 3) * 4 + mm;       // 0..79
  if (ty >= *ntiles) return;
  int n0 = (g & 7) * 128;
  int e = tile_e[ty], m0 = tile_m0[ty];
  int base_slot = offsets[e] + m0;
  int cnt = counts[e] - m0; if (cnt > 128) cnt = 128;

  __shared__ unsigned short As[2][128 * 32];
  __shared__ unsigned short Bs[2][128 * 32];

  int t = threadIdx.x;
  int row = t >> 2, kc = (t & 3) * 8;
  int r0i = base_slot + row;      if (r0i > NSLOT - 1) r0i = NSLOT - 1;
  int r1i = base_slot + 64 + row; if (r1i > NSLOT - 1) r1i = NSLOT - 1;
  const unsigned short* ag0 = H + (size_t)r0i * IDIM + kc;
  const unsigned short* ag1 = H + (size_t)r1i * IDIM + kc;
  const unsigned short* bg0 = W2T + ((size_t)e * DDIM + n0 + row) * IDIM + kc;
  const unsigned short* bg1 = bg0 + (size_t)64 * IDIM;
  int d0 = t * 8, d1 = 2048 + t * 8;

  int lane = t & 63, wv = t >> 6;
  int wm = (wv >> 1) * 64, wn = (wv & 1) * 64;
  int lm = lane & 15, kg = lane >> 4;
  int ao[4], bo[4];
#pragma unroll
  for (int i = 0; i < 4; ++i) {
    ao[i] = (wm + i * 16 + lm) * 32 + kg * 8;
    bo[i] = (wn + i * 16 + lm) * 32 + kg * 8;
  }

  f32x4 acc[4][4];
#pragma unroll
  for (int i = 0; i < 4; ++i)
#pragma unroll
    for (int j = 0; j < 4; ++j) acc[i][j] = 0.f;

  gload_lds16(ag0, As[0] + d0);
  gload_lds16(ag1, As[0] + d1);
  gload_lds16(bg0, Bs[0] + d0);
  gload_lds16(bg1, Bs[0] + d1);

  for (int k0 = 0; k0 < IDIM; k0 += 32) {
    int cur = (k0 >> 5) & 1;
    __syncthreads();
    if (k0 + 32 < IDIM) {
      int nx = cur ^ 1, kn = k0 + 32;
      gload_lds16(ag0 + kn, As[nx] + d0);
      gload_lds16(ag1 + kn, As[nx] + d1);
      gload_lds16(bg0 + kn, Bs[nx] + d0);
      gload_lds16(bg1 + kn, Bs[nx] + d1);
    }
    bf16x8 av[4], bv[4];
#pragma unroll
    for (int i = 0; i < 4; ++i) {
      av[i] = *(const bf16x8*)(As[cur] + ao[i]);
      bv[i] = *(const bf16x8*)(Bs[cur] + bo[i]);
    }
#pragma unroll
    for (int mi = 0; mi < 4; ++mi)
#pragma unroll
      for (int ni = 0; ni < 4; ++ni)
        acc[mi][ni] = __builtin_amdgcn_mfma_f32_16x16x32_bf16(av[mi], bv[ni], acc[mi][ni], 0, 0, 0);
  }

#pragma unroll
  for (int mi = 0; mi < 4; ++mi)
#pragma unroll
    for (int rr = 0; rr < 4; ++rr) {
      int orow = wm + mi * 16 + kg * 4 + rr;
      if (orow < cnt) {
        unsigned short* op = O2 + (size_t)(base_slot + orow) * DDIM + n0;
#pragma unroll
        for (int ni = 0; ni < 4; ++ni)
          op[wn + ni * 16 + lm] = f2bf(acc[mi][ni][rr]);
      }
    }
}

// ---------------- combine: out[t] = O2[slot0] + O2[slot1] (bf16 in, fp32 out) ----------------
__global__ void k_combine(const unsigned short* __restrict__ O2, const int* __restrict__ slot_of,
                          float* __restrict__ out) {
  int tk = blockIdx.x, tt = threadIdx.x;
  int s0 = slot_of[2 * tk], s1 = slot_of[2 * tk + 1];
  us4 a = ((const us4*)(O2 + (size_t)s0 * DDIM))[tt];
  us4 b = ((const us4*)(O2 + (size_t)s1 * DDIM))[tt];
  f32x4 o;
#pragma unroll
  for (int j = 0; j < 4; ++j) o[j] = bf2f(a[j]) + bf2f(b[j]);
  ((f32x4*)(out + (size_t)tk * DDIM))[tt] = o;
}

extern "C" void kernel_launch(void* const* d_in, const int* in_sizes, int n_in,
                              void* d_out, int out_size, void* d_ws, size_t ws_size,
                              hipStream_t stream) {
  const float* x  = (const float*)d_in[0];
  const float* Wg = (const float*)d_in[1];
  const float* W1 = (const float*)d_in[2];
  const float* W2 = (const float*)d_in[3];   // dict order: x, Wg, W1, W2, W3
  const float* W3 = (const float*)d_in[4];
  float* out = (float*)d_out;

  char* ws = (char*)d_ws;
  size_t off = 0;
  unsigned short* Xb = (unsigned short*)(ws + off); off += (size_t)NTOK * DDIM * 2;
  unsigned short* H  = (unsigned short*)(ws + off); off += (size_t)NSLOT * IDIM * 2;
  unsigned short* O2 = (unsigned short*)(ws + off); off += (size_t)NSLOT * DDIM * 2;
  unsigned short* W1T = (unsigned short*)(ws + off); off += (size_t)NEXP * NPAD1 * DDIM * 2;
  unsigned short* W3T = (unsigned short*)(ws + off); off += (size_t)NEXP * NPAD1 * DDIM * 2;
  unsigned short* W2T = (unsigned short*)(ws + off); off += (size_t)NEXP * DDIM * IDIM * 2;
  int* counts  = (int*)(ws + off); off += 64;
  int* offsets = (int*)(ws + off); off += 128;
  int* ntiles  = (int*)(ws + off); off += 64;
  int* tile_e  = (int*)(ws + off); off += MAXT * 4;
  int* tile_m0 = (int*)(ws + off); off += MAXT * 4;
  int* tok_e   = (int*)(ws + off); off += NSLOT * 4;
  float* tok_w = (float*)(ws + off); off += NSLOT * 4;
  int* token_map = (int*)(ws + off); off += NSLOT * 4;
  float* gate_w  = (float*)(ws + off); off += NSLOT * 4;
  int* slot_of   = (int*)(ws + off); off += NSLOT * 4;

  k_front<<<WTBLK + 1024, 256, 0, stream>>>(x, Wg, W1, W3, W2, tok_e, tok_w, Xb,
                                            W1T, W3T, W2T);
  k_scan_scatter<<<NEXP, 256, 0, stream>>>(tok_e, tok_w, counts, offsets, ntiles,
                                           tile_e, tile_m0, token_map, gate_w, slot_of);
  k_gemm1<<<480, 256, 0, stream>>>(Xb, W1T, W3T, token_map, gate_w, ntiles, tile_e,
                                   tile_m0, offsets, counts, H);
  k_gemm2<<<640, 256, 0, stream>>>(H, W2T, ntiles, tile_e, tile_m0, offsets, counts, O2);
  k_combine<<<4096, 256, 0, stream>>>(O2, slot_of, out);
}

// Round 8
// 300.758 us; speedup vs baseline: 1.0628x; 1.0039x over previous
//
#include <hip/hip_runtime.h>

#define NTOK 4096
#define DDIM 1024
#define IDIM 704
#define NEXP 16
#define NSLOT 8192
#define MAXT 128
#define NPAD1 768    // IDIM padded to 128 multiple for gemm1 n-dim
#define WTBLK 4480   // wtrans blocks: W1 1536 + W3 1536 + W2 1408

typedef __attribute__((ext_vector_type(8))) short bf16x8;
typedef __attribute__((ext_vector_type(4))) float f32x4;
typedef __attribute__((ext_vector_type(4))) unsigned short us4;
typedef __attribute__((ext_vector_type(8))) unsigned short us8;

__device__ __forceinline__ unsigned short f2bf(float f) {
  union { float f; unsigned int u; } v; v.f = f;
  unsigned int r = v.u + 0x7fffu + ((v.u >> 16) & 1u);
  return (unsigned short)(r >> 16);
}

__device__ __forceinline__ float bf2f(unsigned short b) {
  union { unsigned int u; float f; } v; v.u = ((unsigned int)b) << 16;
  return v.f;
}

__device__ __forceinline__ void gload_lds16(const void* g, void* l) {
  __builtin_amdgcn_global_load_lds((const __attribute__((address_space(1))) void*)g,
                                   (__attribute__((address_space(3))) void*)l, 16, 0, 0);
}

// ---------------- front: weight transpose (blocks 0..4479) + router (4480..5503) ----------------
__global__ void k_front(const float* __restrict__ x, const float* __restrict__ Wg,
                        const float* __restrict__ W1, const float* __restrict__ W3,
                        const float* __restrict__ W2, int* __restrict__ tok_e,
                        float* __restrict__ tok_w, unsigned short* __restrict__ Xb,
                        unsigned short* __restrict__ W1T, unsigned short* __restrict__ W3T,
                        unsigned short* __restrict__ W2T) {
  int b = blockIdx.x;
  if (b < WTBLK) {
    __shared__ unsigned short lds[2][64 * 64];
    const float* src; unsigned short* dst;
    int ksz, nsz, kx, np, e;
    if (b < 3072) {               // W1: 0..1535, W3: 1536..3071 (16 k x 6 npair x 16 e)
      int which = (b >= 1536) ? 1 : 0;
      int tb = b - which * 1536;
      kx = tb & 15; int rest = tb >> 4; np = rest % 6; e = rest / 6;
      ksz = DDIM; nsz = IDIM;
      src = (which ? W3 : W1) + (size_t)e * DDIM * IDIM;
      dst = (which ? W3T : W1T) + (size_t)e * NPAD1 * DDIM;
    } else {                      // W2: 11 k x 8 npair x 16 e
      int tb = b - 3072;
      kx = tb % 11; int rest = tb / 11; np = rest & 7; e = rest >> 3;
      ksz = IDIM; nsz = DDIM;
      src = W2 + (size_t)e * IDIM * DDIM;
      dst = W2T + (size_t)e * DDIM * IDIM;
    }
    int k0 = kx * 64;
    int t = threadIdx.x;
    int kr4 = (t >> 4) * 4, nc4 = (t & 15) * 4;
    int n0a = np * 128, n0b = n0a + 64;
    bool bvalid = n0b < nsz;      // half B padding only on last W1/W3 n-pair
    f32x4 v0[4], v1[4];
#pragma unroll
    for (int j = 0; j < 4; ++j)
      v0[j] = *(const f32x4*)(src + (size_t)(k0 + kr4 + j) * nsz + n0a + nc4);
    if (bvalid) {
#pragma unroll
      for (int j = 0; j < 4; ++j)
        v1[j] = *(const f32x4*)(src + (size_t)(k0 + kr4 + j) * nsz + n0b + nc4);
    }
    int c8 = kr4 >> 3, half = (kr4 >> 2) & 1;
#pragma unroll
    for (int i = 0; i < 4; ++i) {
      int row = nc4 + i;
      int addr = row * 64 + ((c8 ^ ((row >> 2) & 7)) << 3) + half * 4;
      us4 o0;
#pragma unroll
      for (int j = 0; j < 4; ++j) o0[j] = f2bf(v0[j][i]);
      *(us4*)(lds[0] + addr) = o0;
      if (bvalid) {
        us4 o1;
#pragma unroll
        for (int j = 0; j < 4; ++j) o1[j] = f2bf(v1[j][i]);
        *(us4*)(lds[1] + addr) = o1;
      }
    }
    __syncthreads();
    int nr = t >> 3, kc8 = t & 7;
#pragma unroll
    for (int q = 0; q < 2; ++q) {
      int row = nr + q * 32;
      us8 oA = *(const us8*)(lds[0] + row * 64 + ((kc8 ^ ((row >> 2) & 7)) << 3));
      *(us8*)(dst + (size_t)(n0a + row) * ksz + k0 + kc8 * 8) = oA;
      us8 oB = bvalid ? *(const us8*)(lds[1] + row * 64 + ((kc8 ^ ((row >> 2) & 7)) << 3))
                      : (us8)(unsigned short)0;
      *(us8*)(dst + (size_t)(n0b + row) * ksz + k0 + kc8 * 8) = oB;
    }
    return;
  }
  // ---- router ----
  int rb = b - WTBLK;
  int lane = threadIdx.x & 63;
  int wv = threadIdx.x >> 6;
  int tk = rb * 4 + wv;
  const f32x4* xr = (const f32x4*)(x + (size_t)tk * DDIM);
  us4* xbr = (us4*)(Xb + (size_t)tk * DDIM);
  f32x4 xv[4];
#pragma unroll
  for (int c = 0; c < 4; ++c) {
    xv[c] = xr[c * 64 + lane];
    us4 o;
#pragma unroll
    for (int j = 0; j < 4; ++j) o[j] = f2bf(xv[c][j]);
    xbr[c * 64 + lane] = o;
  }
  float p[NEXP];
#pragma unroll
  for (int e = 0; e < NEXP; ++e) {
    const f32x4* wr = (const f32x4*)(Wg + (size_t)e * DDIM);
    float s = 0.f;
#pragma unroll
    for (int c = 0; c < 4; ++c) {
      f32x4 w4 = wr[c * 64 + lane];
      s += xv[c][0]*w4[0] + xv[c][1]*w4[1] + xv[c][2]*w4[2] + xv[c][3]*w4[3];
    }
    p[e] = s;
  }
#pragma unroll
  for (int off = 32; off >= 1; off >>= 1) {
#pragma unroll
    for (int e = 0; e < NEXP; ++e) p[e] += __shfl_xor(p[e], off);
  }
  int i0 = 0; float b0 = p[0];
#pragma unroll
  for (int e = 1; e < NEXP; ++e) if (p[e] > b0) { b0 = p[e]; i0 = e; }
  int i1 = -1; float b1 = -3.4e38f;
#pragma unroll
  for (int e = 0; e < NEXP; ++e) if (e != i0 && p[e] > b1) { b1 = p[e]; i1 = e; }
  if (lane == 0) {
    float w0 = 1.f / (1.f + __expf(b1 - b0));   // renormalized top-2 softmax weight
    tok_e[2*tk] = i0; tok_e[2*tk+1] = i1;
    tok_w[2*tk] = w0; tok_w[2*tk+1] = 1.f - w0;
  }
}

// ---------------- count+scan+scatter: 16 blocks, no atomics, NO register arrays ----------------
// Wave w owns contiguous indices [w*2048, (w+1)*2048). Pass 1: stream tok_e
// (coalesced, L2-hot), 16 ballots/segment -> per-wave per-expert counts in
// registers (ce[16]); expert-eb masks stashed in LDS. One barrier. Pass 2:
// deterministic rank-and-scatter from LDS masks. No scratch spills.
__global__ void k_scan_scatter(const int* __restrict__ tok_e, const float* __restrict__ tok_w,
                               int* __restrict__ counts, int* __restrict__ offsets,
                               int* __restrict__ ntiles, int* __restrict__ tile_e,
                               int* __restrict__ tile_m0, int* __restrict__ token_map,
                               float* __restrict__ gate_w, int* __restrict__ slot_of) {
  int eb = blockIdx.x;
  int t = threadIdx.x, lane = t & 63, wv = t >> 6;
  __shared__ unsigned long long masks[4][32];   // expert-eb ballot per [wave][seg]
  __shared__ int wcnt[4][NEXP];                 // per-wave per-expert counts
  __shared__ int counts_s[NEXP];
  int ce[NEXP];
#pragma unroll
  for (int e = 0; e < NEXP; ++e) ce[e] = 0;
#pragma unroll 1
  for (int s = 0; s < 32; ++s) {
    int te = tok_e[wv * 2048 + s * 64 + lane];
#pragma unroll
    for (int e = 0; e < NEXP; ++e) {
      unsigned long long m = __ballot(te == e);
      ce[e] += (int)__popcll(m);
      if (e == eb && lane == 0) masks[wv][s] = m;
    }
  }
  if (lane == 0) {
#pragma unroll
    for (int e = 0; e < NEXP; ++e) wcnt[wv][e] = ce[e];
  }
  __syncthreads();
  if (t < NEXP) {
    int s = wcnt[0][t] + wcnt[1][t] + wcnt[2][t] + wcnt[3][t];
    counts_s[t] = s;
    if (eb == 0) counts[t] = s;
  }
  __syncthreads();
  if (eb == 0 && t == 0) {
    int acc = 0, nt = 0;
    for (int e = 0; e < NEXP; ++e) {
      offsets[e] = acc;
      int cc = counts_s[e];
      for (int m0 = 0; m0 < cc; m0 += 128) { tile_e[nt] = e; tile_m0[nt] = m0; ++nt; }
      acc += cc;
    }
    offsets[NEXP] = acc;
    *ntiles = nt;
  }
  int run = 0;
  for (int e = 0; e < eb; ++e) run += counts_s[e];            // expert base
  for (int w = 0; w < wv; ++w) run += wcnt[w][eb];            // wave base
  unsigned long long below = (lane == 63) ? 0x7fffffffffffffffull : ((1ull << lane) - 1ull);
#pragma unroll 1
  for (int s = 0; s < 32; ++s) {
    unsigned long long m = masks[wv][s];
    if ((m >> lane) & 1ull) {
      int i = wv * 2048 + s * 64 + lane;
      int slot = run + (int)__popcll(m & below);
      token_map[slot] = i >> 1;
      gate_w[slot] = tok_w[i];
      slot_of[i] = slot;
    }
    run += (int)__popcll(m);
  }
}

// ---------------- GEMM1: 128x128, double-buffered LDS, XCD-swizzled ----------------
__global__ __launch_bounds__(256, 2)
void k_gemm1(const unsigned short* __restrict__ Xb, const unsigned short* __restrict__ W1T,
             const unsigned short* __restrict__ W3T, const int* __restrict__ token_map,
             const float* __restrict__ gate_w, const int* __restrict__ ntiles,
             const int* __restrict__ tile_e, const int* __restrict__ tile_m0,
             const int* __restrict__ offsets, const int* __restrict__ counts,
             unsigned short* __restrict__ H) {
  int idx = blockIdx.x;
  int xcd = idx & 7, r = idx >> 3;
  int g = (r >> 2) * 8 + xcd;       // 0..119
  int mm = r & 3;
  int ty = (g / 6) * 4 + mm;        // 0..79
  if (ty >= *ntiles) return;
  int n0 = (g % 6) * 128;
  int e = tile_e[ty], m0 = tile_m0[ty];
  int base_slot = offsets[e] + m0;
  int cnt = counts[e] - m0; if (cnt > 128) cnt = 128;

  __shared__ unsigned short As[2][128 * 32];
  __shared__ unsigned short B1s[2][128 * 32];
  __shared__ unsigned short B3s[2][128 * 32];

  int t = threadIdx.x;
  int row = t >> 2, kc = (t & 3) * 8;
  int r0i = base_slot + row;      if (r0i > NSLOT - 1) r0i = NSLOT - 1;
  int r1i = base_slot + 64 + row; if (r1i > NSLOT - 1) r1i = NSLOT - 1;
  const unsigned short* ag0 = Xb + (size_t)token_map[r0i] * DDIM + kc;
  const unsigned short* ag1 = Xb + (size_t)token_map[r1i] * DDIM + kc;
  const unsigned short* b1g0 = W1T + ((size_t)e * NPAD1 + n0 + row) * DDIM + kc;
  const unsigned short* b1g1 = b1g0 + (size_t)64 * DDIM;
  const unsigned short* b3g0 = W3T + ((size_t)e * NPAD1 + n0 + row) * DDIM + kc;
  const unsigned short* b3g1 = b3g0 + (size_t)64 * DDIM;
  int d0 = t * 8, d1 = 2048 + t * 8;

  int lane = t & 63, wv = t >> 6;
  int wm = (wv >> 1) * 64, wn = (wv & 1) * 64;
  int lm = lane & 15, kg = lane >> 4;
  int ao[4], bo[4];
#pragma unroll
  for (int i = 0; i < 4; ++i) {
    ao[i] = (wm + i * 16 + lm) * 32 + kg * 8;
    bo[i] = (wn + i * 16 + lm) * 32 + kg * 8;
  }

  f32x4 acc1[4][4], acc3[4][4];
#pragma unroll
  for (int i = 0; i < 4; ++i)
#pragma unroll
    for (int j = 0; j < 4; ++j) { acc1[i][j] = 0.f; acc3[i][j] = 0.f; }

  gload_lds16(ag0, As[0] + d0);
  gload_lds16(ag1, As[0] + d1);
  gload_lds16(b1g0, B1s[0] + d0);
  gload_lds16(b1g1, B1s[0] + d1);
  gload_lds16(b3g0, B3s[0] + d0);
  gload_lds16(b3g1, B3s[0] + d1);

  for (int k0 = 0; k0 < DDIM; k0 += 32) {
    int cur = (k0 >> 5) & 1;
    __syncthreads();
    if (k0 + 32 < DDIM) {
      int nx = cur ^ 1, kn = k0 + 32;
      gload_lds16(ag0 + kn, As[nx] + d0);
      gload_lds16(ag1 + kn, As[nx] + d1);
      gload_lds16(b1g0 + kn, B1s[nx] + d0);
      gload_lds16(b1g1 + kn, B1s[nx] + d1);
      gload_lds16(b3g0 + kn, B3s[nx] + d0);
      gload_lds16(b3g1 + kn, B3s[nx] + d1);
    }
    bf16x8 av[4], b1v[4], b3v[4];
#pragma unroll
    for (int i = 0; i < 4; ++i) {
      av[i]  = *(const bf16x8*)(As[cur] + ao[i]);
      b1v[i] = *(const bf16x8*)(B1s[cur] + bo[i]);
      b3v[i] = *(const bf16x8*)(B3s[cur] + bo[i]);
    }
#pragma unroll
    for (int mi = 0; mi < 4; ++mi)
#pragma unroll
      for (int ni = 0; ni < 4; ++ni) {
        acc1[mi][ni] = __builtin_amdgcn_mfma_f32_16x16x32_bf16(av[mi], b1v[ni], acc1[mi][ni], 0, 0, 0);
        acc3[mi][ni] = __builtin_amdgcn_mfma_f32_16x16x32_bf16(av[mi], b3v[ni], acc3[mi][ni], 0, 0, 0);
      }
  }

#pragma unroll
  for (int mi = 0; mi < 4; ++mi)
#pragma unroll
    for (int rr = 0; rr < 4; ++rr) {
      int orow = wm + mi * 16 + kg * 4 + rr;
      if (orow < cnt) {
        int slot = base_slot + orow;
        float gw = gate_w[slot];
        unsigned short* hrow = H + (size_t)slot * IDIM;
#pragma unroll
        for (int ni = 0; ni < 4; ++ni) {
          int nn = n0 + wn + ni * 16 + lm;
          if (nn < IDIM) {
            float v1 = acc1[mi][ni][rr];
            float v3 = acc3[mi][ni][rr];
            float hh = v1 / (1.f + __expf(-v1)) * v3 * gw;
            hrow[nn] = f2bf(hh);
          }
        }
      }
    }
}

// ---------------- GEMM2: 128x128, double-buffered LDS, bf16 output ----------------
__global__ __launch_bounds__(256, 3)
void k_gemm2(const unsigned short* __restrict__ H, const unsigned short* __restrict__ W2T,
             const int* __restrict__ ntiles, const int* __restrict__ tile_e,
             const int* __restrict__ tile_m0, const int* __restrict__ offsets,
             const int* __restrict__ counts, unsigned short* __restrict__ O2) {
  int idx = blockIdx.x;
  int xcd = idx & 7, r = idx >> 3;
  int g = (r >> 2) * 8 + xcd;       // 0..159
  int mm = r & 3;
  int ty = (g >> 3) * 4 + mm;       // 0..79
  if (ty >= *ntiles) return;
  int n0 = (g & 7) * 128;
  int e = tile_e[ty], m0 = tile_m0[ty];
  int base_slot = offsets[e] + m0;
  int cnt = counts[e] - m0; if (cnt > 128) cnt = 128;

  __shared__ unsigned short As[2][128 * 32];
  __shared__ unsigned short Bs[2][128 * 32];

  int t = threadIdx.x;
  int row = t >> 2, kc = (t & 3) * 8;
  int r0i = base_slot + row;      if (r0i > NSLOT - 1) r0i = NSLOT - 1;
  int r1i = base_slot + 64 + row; if (r1i > NSLOT - 1) r1i = NSLOT - 1;
  const unsigned short* ag0 = H + (size_t)r0i * IDIM + kc;
  const unsigned short* ag1 = H + (size_t)r1i * IDIM + kc;
  const unsigned short* bg0 = W2T + ((size_t)e * DDIM + n0 + row) * IDIM + kc;
  const unsigned short* bg1 = bg0 + (size_t)64 * IDIM;
  int d0 = t * 8, d1 = 2048 + t * 8;

  int lane = t & 63, wv = t >> 6;
  int wm = (wv >> 1) * 64, wn = (wv & 1) * 64;
  int lm = lane & 15, kg = lane >> 4;
  int ao[4], bo[4];
#pragma unroll
  for (int i = 0; i < 4; ++i) {
    ao[i] = (wm + i * 16 + lm) * 32 + kg * 8;
    bo[i] = (wn + i * 16 + lm) * 32 + kg * 8;
  }

  f32x4 acc[4][4];
#pragma unroll
  for (int i = 0; i < 4; ++i)
#pragma unroll
    for (int j = 0; j < 4; ++j) acc[i][j] = 0.f;

  gload_lds16(ag0, As[0] + d0);
  gload_lds16(ag1, As[0] + d1);
  gload_lds16(bg0, Bs[0] + d0);
  gload_lds16(bg1, Bs[0] + d1);

  for (int k0 = 0; k0 < IDIM; k0 += 32) {
    int cur = (k0 >> 5) & 1;
    __syncthreads();
    if (k0 + 32 < IDIM) {
      int nx = cur ^ 1, kn = k0 + 32;
      gload_lds16(ag0 + kn, As[nx] + d0);
      gload_lds16(ag1 + kn, As[nx] + d1);
      gload_lds16(bg0 + kn, Bs[nx] + d0);
      gload_lds16(bg1 + kn, Bs[nx] + d1);
    }
    bf16x8 av[4], bv[4];
#pragma unroll
    for (int i = 0; i < 4; ++i) {
      av[i] = *(const bf16x8*)(As[cur] + ao[i]);
      bv[i] = *(const bf16x8*)(Bs[cur] + bo[i]);
    }
#pragma unroll
    for (int mi = 0; mi < 4; ++mi)
#pragma unroll
      for (int ni = 0; ni < 4; ++ni)
        acc[mi][ni] = __builtin_amdgcn_mfma_f32_16x16x32_bf16(av[mi], bv[ni], acc[mi][ni], 0, 0, 0);
  }

#pragma unroll
  for (int mi = 0; mi < 4; ++mi)
#pragma unroll
    for (int rr = 0; rr < 4; ++rr) {
      int orow = wm + mi * 16 + kg * 4 + rr;
      if (orow < cnt) {
        unsigned short* op = O2 + (size_t)(base_slot + orow) * DDIM + n0;
#pragma unroll
        for (int ni = 0; ni < 4; ++ni)
          op[wn + ni * 16 + lm] = f2bf(acc[mi][ni][rr]);
      }
    }
}

// ---------------- combine: out[t] = O2[slot0] + O2[slot1] (bf16 in, fp32 out) ----------------
__global__ void k_combine(const unsigned short* __restrict__ O2, const int* __restrict__ slot_of,
                          float* __restrict__ out) {
  int tk = blockIdx.x, tt = threadIdx.x;
  int s0 = slot_of[2 * tk], s1 = slot_of[2 * tk + 1];
  us4 a = ((const us4*)(O2 + (size_t)s0 * DDIM))[tt];
  us4 b = ((const us4*)(O2 + (size_t)s1 * DDIM))[tt];
  f32x4 o;
#pragma unroll
  for (int j = 0; j < 4; ++j) o[j] = bf2f(a[j]) + bf2f(b[j]);
  ((f32x4*)(out + (size_t)tk * DDIM))[tt] = o;
}

extern "C" void kernel_launch(void* const* d_in, const int* in_sizes, int n_in,
                              void* d_out, int out_size, void* d_ws, size_t ws_size,
                              hipStream_t stream) {
  const float* x  = (const float*)d_in[0];
  const float* Wg = (const float*)d_in[1];
  const float* W1 = (const float*)d_in[2];
  const float* W2 = (const float*)d_in[3];   // dict order: x, Wg, W1, W2, W3
  const float* W3 = (const float*)d_in[4];
  float* out = (float*)d_out;

  char* ws = (char*)d_ws;
  size_t off = 0;
  unsigned short* Xb = (unsigned short*)(ws + off); off += (size_t)NTOK * DDIM * 2;
  unsigned short* H  = (unsigned short*)(ws + off); off += (size_t)NSLOT * IDIM * 2;
  unsigned short* O2 = (unsigned short*)(ws + off); off += (size_t)NSLOT * DDIM * 2;
  unsigned short* W1T = (unsigned short*)(ws + off); off += (size_t)NEXP * NPAD1 * DDIM * 2;
  unsigned short* W3T = (unsigned short*)(ws + off); off += (size_t)NEXP * NPAD1 * DDIM * 2;
  unsigned short* W2T = (unsigned short*)(ws + off); off += (size_t)NEXP * DDIM * IDIM * 2;
  int* counts  = (int*)(ws + off); off += 64;
  int* offsets = (int*)(ws + off); off += 128;
  int* ntiles  = (int*)(ws + off); off += 64;
  int* tile_e  = (int*)(ws + off); off += MAXT * 4;
  int* tile_m0 = (int*)(ws + off); off += MAXT * 4;
  int* tok_e   = (int*)(ws + off); off += NSLOT * 4;
  float* tok_w = (float*)(ws + off); off += NSLOT * 4;
  int* token_map = (int*)(ws + off); off += NSLOT * 4;
  float* gate_w  = (float*)(ws + off); off += NSLOT * 4;
  int* slot_of   = (int*)(ws + off); off += NSLOT * 4;

  k_front<<<WTBLK + 1024, 256, 0, stream>>>(x, Wg, W1, W3, W2, tok_e, tok_w, Xb,
                                            W1T, W3T, W2T);
  k_scan_scatter<<<NEXP, 256, 0, stream>>>(tok_e, tok_w, counts, offsets, ntiles,
                                           tile_e, tile_m0, token_map, gate_w, slot_of);
  k_gemm1<<<480, 256, 0, stream>>>(Xb, W1T, W3T, token_map, gate_w, ntiles, tile_e,
                                   tile_m0, offsets, counts, H);
  k_gemm2<<<640, 256, 0, stream>>>(H, W2T, ntiles, tile_e, tile_m0, offsets, counts, O2);
  k_combine<<<4096, 256, 0, stream>>>(O2, slot_of, out);
}